// Round 1
// baseline (394.174 us; speedup 1.0000x reference)
//
#include <hip/hip_runtime.h>
#include <hip/hip_cooperative_groups.h>
#include <math.h>

namespace cg = cooperative_groups;

#define TT 4096
#define DM 1024
#define BB 4
#define BT (BB * TT)
#define SENTINEL 0x7fffffff

// ws layout (bytes):
//   Q    : float[BT*2]  @ 0        (131072)
//   K    : float[BT*2]  @ 131072   (131072)  (interleaved k0,k1 pairs)
//   idx  : int[BT]      @ 262144   (65536)
//   rep  : int[BT]      @ 327680   (65536)
//   list : int[BT]      @ 393216   (65536)
//   cnt  : int          @ 458752   (4)

__device__ __forceinline__ float dot4(const float4 a, const float4 b) {
    return a.x * b.x + a.y * b.y + a.z * b.z + a.w * b.w;
}

// ============================================================================
// Fused cooperative kernel: all four phases, 3 grid syncs, grid-stride phases.
// 1024 blocks x 256 threads, co-resident (32KB LDS, <=128 VGPR via bounds).
// ============================================================================
__global__ __launch_bounds__(256, 4) void fused_kernel(
    const float* __restrict__ x, const float* __restrict__ wq,
    const float* __restrict__ wk, const float* __restrict__ wv,
    float* __restrict__ Q, float* __restrict__ K,
    int* __restrict__ idx, int* __restrict__ rep,
    int* __restrict__ list, int* __restrict__ cnt,
    float* __restrict__ out)
{
    __shared__ union {
        float4 w[4][256];   // 16 KB, phase 0 (Q/K weights)
        float2 ks[TT];      // 32 KB, phase 1 (K prefix)
    } sm;

    const int tid  = threadIdx.x;
    const int bid  = blockIdx.x;
    const int nblk = gridDim.x;
    const int wave = tid >> 6, lane = tid & 63;
    cg::grid_group grid = cg::this_grid();

    // ---------------- phase 0: Q,K projection + init rep/cnt ----------------
    sm.w[0][tid] = ((const float4*)(wq))[tid];
    sm.w[1][tid] = ((const float4*)(wq + DM))[tid];
    sm.w[2][tid] = ((const float4*)(wk))[tid];
    sm.w[3][tid] = ((const float4*)(wk + DM))[tid];
    for (int i = bid * 256 + tid; i < BT; i += nblk * 256) rep[i] = SENTINEL;
    if (bid == 0 && tid == 0) cnt[0] = 0;
    __syncthreads();

    for (int vb = bid; vb < BT / 4; vb += nblk) {
        const int row = vb * 4 + wave;
        const float4* xr = (const float4*)(x + (size_t)row * DM);
        float s0 = 0.f, s1 = 0.f, s2 = 0.f, s3 = 0.f;
        #pragma unroll
        for (int j = 0; j < 4; ++j) {
            const float4 xv = xr[j * 64 + lane];
            s0 += dot4(xv, sm.w[0][j * 64 + lane]);
            s1 += dot4(xv, sm.w[1][j * 64 + lane]);
            s2 += dot4(xv, sm.w[2][j * 64 + lane]);
            s3 += dot4(xv, sm.w[3][j * 64 + lane]);
        }
        #pragma unroll
        for (int off = 32; off > 0; off >>= 1) {
            s0 += __shfl_down(s0, off);
            s1 += __shfl_down(s1, off);
            s2 += __shfl_down(s2, off);
            s3 += __shfl_down(s3, off);
        }
        if (lane == 0) {
            ((float2*)Q)[row] = make_float2(s0, s1);
            ((float2*)K)[row] = make_float2(s2, s3);
        }
    }

    grid.sync();

    // ---------------- phase 1: causal argmax, balanced (tg, 1023-tg) --------
    for (int i = bid; i < 1024; i += nblk) {
        #pragma unroll
        for (int slot = 0; slot < 4; ++slot) {
            const int b  = slot;
            const int tg = (slot & 1) ? (1023 - i) : i;   // constant work/block
            const int nfill = tg * 4 + 4;
            const float2* kb = (const float2*)K + (size_t)b * TT;
            for (int k2 = tid; k2 < nfill; k2 += 256) sm.ks[k2] = kb[k2];
            __syncthreads();

            const int t = tg * 4 + wave;
            const float2 q = ((const float2*)Q)[b * TT + t];
            const float4* kp = (const float4*)sm.ks;   // pair p -> points 2p,2p+1

            float best = -INFINITY;
            int bi = SENTINEL;
            int p = lane;
            while (2 * (p + 64) + 1 <= t) {
                const float4 a = kp[p];
                const float4 c = kp[p + 64];
                const float c0 = q.x * a.x + q.y * a.y;
                const float c1 = q.x * a.z + q.y * a.w;
                const float c2 = q.x * c.x + q.y * c.y;
                const float c3 = q.x * c.z + q.y * c.w;
                if (c0 > best) { best = c0; bi = 2 * p; }
                if (c1 > best) { best = c1; bi = 2 * p + 1; }
                if (c2 > best) { best = c2; bi = 2 * (p + 64); }
                if (c3 > best) { best = c3; bi = 2 * (p + 64) + 1; }
                p += 128;
            }
            while (2 * p <= t) {
                const float4 a = kp[p];
                const float c0 = q.x * a.x + q.y * a.y;
                if (c0 > best) { best = c0; bi = 2 * p; }
                if (2 * p + 1 <= t) {
                    const float c1 = q.x * a.z + q.y * a.w;
                    if (c1 > best) { best = c1; bi = 2 * p + 1; }
                }
                p += 64;
            }
            #pragma unroll
            for (int off = 32; off > 0; off >>= 1) {
                const float ov = __shfl_down(best, off);
                const int   oi = __shfl_down(bi, off);
                if (ov > best || (ov == best && oi < bi)) { best = ov; bi = oi; }
            }
            if (lane == 0) {
                idx[b * TT + t] = bi;
                const int old = atomicMin(&rep[b * TT + bi], t);
                if (old == SENTINEL) {
                    const int pp = atomicAdd(cnt, 1);
                    list[pp] = b * TT + bi;
                }
            }
            __syncthreads();   // before next slot overwrites sm.ks
        }
    }

    grid.sync();

    // ---------------- phase 2: V rows for unique sources --------------------
    const int n = cnt[0];
    for (int vb = bid; vb < 1024; vb += nblk) {
        const int slice = vb >> 4;
        const int usub  = vb & 15;
        const int e0 = slice * 16 + wave * 4;
        float4 w[4][4];
        #pragma unroll
        for (int r = 0; r < 4; ++r) {
            const float4* wr = (const float4*)(wv + (size_t)(e0 + r) * DM);
            #pragma unroll
            for (int j = 0; j < 4; ++j) w[r][j] = wr[j * 64 + lane];
        }
        for (int li = usub; li < n; li += 16) {
            const int bs = list[li];
            const int b  = bs >> 12;
            const int r  = rep[bs];
            const float4* xr = (const float4*)(x + (size_t)bs * DM);
            float4 xv[4];
            #pragma unroll
            for (int j = 0; j < 4; ++j) xv[j] = xr[j * 64 + lane];
            float s0 = 0.f, s1 = 0.f, s2 = 0.f, s3 = 0.f;
            #pragma unroll
            for (int j = 0; j < 4; ++j) {
                s0 += dot4(w[0][j], xv[j]);
                s1 += dot4(w[1][j], xv[j]);
                s2 += dot4(w[2][j], xv[j]);
                s3 += dot4(w[3][j], xv[j]);
            }
            #pragma unroll
            for (int off = 32; off > 0; off >>= 1) {
                s0 += __shfl_down(s0, off);
                s1 += __shfl_down(s1, off);
                s2 += __shfl_down(s2, off);
                s3 += __shfl_down(s3, off);
            }
            if (lane == 0)
                *(float4*)(out + ((size_t)(b * TT + r)) * DM + e0) = make_float4(s0, s1, s2, s3);
        }
    }

    grid.sync();

    // ---------------- phase 3: broadcast representative rows ----------------
    for (int bt = bid; bt < BT; bt += nblk) {
        const int b = bt >> 12, t = bt & (TT - 1);
        const int s = idx[bt];
        const int r = rep[b * TT + s];
        if (r == t) continue;
        const float4* src = (const float4*)(out + ((size_t)(b * TT + r)) * DM);
        float4* dst = (float4*)(out + (size_t)bt * DM);
        dst[tid] = src[tid];
    }
}

// ============================================================================
// Fallback path: the verified 4-kernel chain (used if cooperative launch
// is unavailable) — identical to the previous best kernel.
// ============================================================================
__global__ __launch_bounds__(256) void qk_kernel(const float* __restrict__ x,
                                                 const float* __restrict__ wq,
                                                 const float* __restrict__ wk,
                                                 float* __restrict__ Q,
                                                 float* __restrict__ K,
                                                 int* __restrict__ rep,
                                                 int* __restrict__ cnt) {
    __shared__ float4 wqs0[256], wqs1[256], wks0[256], wks1[256];
    const int tid = threadIdx.x;
    const int row0 = blockIdx.x * 4;

    wqs0[tid] = ((const float4*)(wq))[tid];
    wqs1[tid] = ((const float4*)(wq + DM))[tid];
    wks0[tid] = ((const float4*)(wk))[tid];
    wks1[tid] = ((const float4*)(wk + DM))[tid];

    if (tid < 4) rep[row0 + tid] = SENTINEL;
    if (blockIdx.x == 0 && tid == 4) cnt[0] = 0;
    __syncthreads();

    const int wave = tid >> 6, lane = tid & 63;
    const int row = row0 + wave;
    const float4* xr = (const float4*)(x + (size_t)row * DM);

    float s0 = 0.f, s1 = 0.f, s2 = 0.f, s3 = 0.f;
    #pragma unroll
    for (int j = 0; j < 4; ++j) {
        const float4 xv = xr[j * 64 + lane];
        s0 += dot4(xv, wqs0[j * 64 + lane]);
        s1 += dot4(xv, wqs1[j * 64 + lane]);
        s2 += dot4(xv, wks0[j * 64 + lane]);
        s3 += dot4(xv, wks1[j * 64 + lane]);
    }
    #pragma unroll
    for (int off = 32; off > 0; off >>= 1) {
        s0 += __shfl_down(s0, off);
        s1 += __shfl_down(s1, off);
        s2 += __shfl_down(s2, off);
        s3 += __shfl_down(s3, off);
    }
    if (lane == 0) {
        ((float2*)Q)[row] = make_float2(s0, s1);
        ((float2*)K)[row] = make_float2(s2, s3);
    }
}

__global__ __launch_bounds__(256) void argmax_kernel(const float* __restrict__ Q,
                                                     const float* __restrict__ K,
                                                     int* __restrict__ idx,
                                                     int* __restrict__ rep,
                                                     int* __restrict__ list,
                                                     int* __restrict__ cnt) {
    __shared__ float2 ks[TT];
    const int b  = blockIdx.x >> 10;
    const int tg = blockIdx.x & 1023;
    const int tid = threadIdx.x;
    const int nfill = tg * 4 + 4;

    const float2* kb = (const float2*)(K + (size_t)b * TT * 2);
    for (int i = tid; i < nfill; i += 256) ks[i] = kb[i];
    __syncthreads();

    const int wave = tid >> 6, lane = tid & 63;
    const int t = tg * 4 + wave;
    const float2 q = ((const float2*)Q)[b * TT + t];
    const float4* kp = (const float4*)ks;

    float best = -INFINITY;
    int bi = 0x7fffffff;
    int p = lane;
    while (2 * (p + 64) + 1 <= t) {
        const float4 a = kp[p];
        const float4 c = kp[p + 64];
        const float c0 = q.x * a.x + q.y * a.y;
        const float c1 = q.x * a.z + q.y * a.w;
        const float c2 = q.x * c.x + q.y * c.y;
        const float c3 = q.x * c.z + q.y * c.w;
        if (c0 > best) { best = c0; bi = 2 * p; }
        if (c1 > best) { best = c1; bi = 2 * p + 1; }
        if (c2 > best) { best = c2; bi = 2 * (p + 64); }
        if (c3 > best) { best = c3; bi = 2 * (p + 64) + 1; }
        p += 128;
    }
    while (2 * p <= t) {
        const float4 a = kp[p];
        const float c0 = q.x * a.x + q.y * a.y;
        if (c0 > best) { best = c0; bi = 2 * p; }
        if (2 * p + 1 <= t) {
            const float c1 = q.x * a.z + q.y * a.w;
            if (c1 > best) { best = c1; bi = 2 * p + 1; }
        }
        p += 64;
    }
    #pragma unroll
    for (int off = 32; off > 0; off >>= 1) {
        const float ov = __shfl_down(best, off);
        const int   oi = __shfl_down(bi, off);
        if (ov > best || (ov == best && oi < bi)) { best = ov; bi = oi; }
    }
    if (lane == 0) {
        idx[b * TT + t] = bi;
        const int old = atomicMin(&rep[b * TT + bi], t);
        if (old == SENTINEL) {
            const int pp = atomicAdd(cnt, 1);
            list[pp] = b * TT + bi;
        }
    }
}

__global__ __launch_bounds__(256) void vrow_kernel(const float* __restrict__ x,
                                                   const float* __restrict__ wv,
                                                   const int* __restrict__ rep,
                                                   const int* __restrict__ list,
                                                   const int* __restrict__ cnt,
                                                   float* __restrict__ out) {
    const int tid = threadIdx.x, wave = tid >> 6, lane = tid & 63;
    const int slice = blockIdx.x >> 4;
    const int usub  = blockIdx.x & 15;
    const int e0 = slice * 16 + wave * 4;

    float4 w[4][4];
    #pragma unroll
    for (int r = 0; r < 4; ++r) {
        const float4* wr = (const float4*)(wv + (size_t)(e0 + r) * DM);
        #pragma unroll
        for (int j = 0; j < 4; ++j) w[r][j] = wr[j * 64 + lane];
    }

    const int n = cnt[0];
    for (int li = usub; li < n; li += 16) {
        const int bs = list[li];
        const int b  = bs >> 12;
        const int r  = rep[bs];
        const float4* xr = (const float4*)(x + (size_t)bs * DM);
        float4 xv[4];
        #pragma unroll
        for (int j = 0; j < 4; ++j) xv[j] = xr[j * 64 + lane];

        float s0 = 0.f, s1 = 0.f, s2 = 0.f, s3 = 0.f;
        #pragma unroll
        for (int j = 0; j < 4; ++j) {
            s0 += dot4(w[0][j], xv[j]);
            s1 += dot4(w[1][j], xv[j]);
            s2 += dot4(w[2][j], xv[j]);
            s3 += dot4(w[3][j], xv[j]);
        }
        #pragma unroll
        for (int off = 32; off > 0; off >>= 1) {
            s0 += __shfl_down(s0, off);
            s1 += __shfl_down(s1, off);
            s2 += __shfl_down(s2, off);
            s3 += __shfl_down(s3, off);
        }
        if (lane == 0)
            *(float4*)(out + ((size_t)(b * TT + r)) * DM + e0) = make_float4(s0, s1, s2, s3);
    }
}

__global__ __launch_bounds__(256) void gather_kernel(const int* __restrict__ idx,
                                                     const int* __restrict__ rep,
                                                     float* __restrict__ out) {
    const int bt = blockIdx.x;
    const int b = bt >> 12, t = bt & (TT - 1);
    const int s = idx[bt];
    const int r = rep[b * TT + s];
    if (r == t) return;
    const float4* src = (const float4*)(out + ((size_t)(b * TT + r)) * DM);
    float4* dst = (float4*)(out + (size_t)bt * DM);
    dst[threadIdx.x] = src[threadIdx.x];
}

extern "C" void kernel_launch(void* const* d_in, const int* in_sizes, int n_in,
                              void* d_out, int out_size, void* d_ws, size_t ws_size,
                              hipStream_t stream) {
    const float* x  = (const float*)d_in[0];
    const float* wq = (const float*)d_in[1];
    const float* wk = (const float*)d_in[2];
    const float* wv = (const float*)d_in[3];
    float* out = (float*)d_out;

    char* ws = (char*)d_ws;
    float* Q    = (float*)(ws);
    float* K    = (float*)(ws + 131072);
    int*   idx  = (int*)  (ws + 262144);
    int*   rep  = (int*)  (ws + 327680);
    int*   list = (int*)  (ws + 393216);
    int*   cnt  = (int*)  (ws + 458752);

    // Cooperative grid size: query once; cap at 1024 (4 blocks/CU x 256 CUs).
    static int coop_grid = -2;   // -2 = untested, -1 = unavailable
    if (coop_grid == -2) {
        int occ = 0;
        if (hipOccupancyMaxActiveBlocksPerMultiprocessor(
                &occ, (const void*)fused_kernel, 256, 0) == hipSuccess && occ > 0) {
            coop_grid = occ * 256;            // 256 CUs on MI355X
            if (coop_grid > 1024) coop_grid = 1024;
        } else {
            coop_grid = -1;
        }
    }

    bool done = false;
    if (coop_grid > 0) {
        void* args[] = {(void*)&x, (void*)&wq, (void*)&wk, (void*)&wv,
                        (void*)&Q, (void*)&K, (void*)&idx, (void*)&rep,
                        (void*)&list, (void*)&cnt, (void*)&out};
        hipError_t e = hipLaunchCooperativeKernel((const void*)fused_kernel,
                                                  dim3(coop_grid), dim3(256),
                                                  args, 0, stream);
        if (e == hipSuccess) done = true;
        else coop_grid = -1;   // don't retry on later calls
    }

    if (!done) {
        qk_kernel<<<BT / 4, 256, 0, stream>>>(x, wq, wk, Q, K, rep, cnt);
        argmax_kernel<<<4096, 256, 0, stream>>>(Q, K, idx, rep, list, cnt);
        vrow_kernel<<<1024, 256, 0, stream>>>(x, wv, rep, list, cnt, out);
        gather_kernel<<<BT, 256, 0, stream>>>(idx, rep, out);
    }
}

// Round 3
// 211.907 us; speedup vs baseline: 1.8601x; 1.8601x over previous
//
#include <hip/hip_runtime.h>
#include <math.h>

#define TT 4096
#define DM 1024
#define BB 4
#define BT (BB * TT)
#define SENTINEL 0x7fffffff

// ws layout (bytes):
//   Q    : float[BT*2]  @ 0        (131072)
//   K    : float[BT*2]  @ 131072   (131072)  (interleaved k0,k1 pairs)
//   idx  : int[BT]      @ 262144   (65536)
//   rep  : int[BT]      @ 327680   (65536)
//   list : int[BT]      @ 393216   (65536)
//   cnt  : int          @ 458752   (4)

__device__ __forceinline__ float dot4(const float4 a, const float4 b) {
    return a.x * b.x + a.y * b.y + a.z * b.z + a.w * b.w;
}

// ---------- Kernel 1: Q,K projection. 8 rows per block (wave does 2 rows),
//            weights staged once in LDS. Also init rep[] and cnt. ----------
__global__ __launch_bounds__(256) void qk_kernel(const float* __restrict__ x,
                                                 const float* __restrict__ wq,
                                                 const float* __restrict__ wk,
                                                 float* __restrict__ Q,
                                                 float* __restrict__ K,
                                                 int* __restrict__ rep,
                                                 int* __restrict__ cnt) {
    __shared__ float4 ws[4][256];   // wq row0, wq row1, wk row0, wk row1 (16 KB)
    const int tid = threadIdx.x;
    const int row0 = blockIdx.x * 8;

    ws[0][tid] = ((const float4*)(wq))[tid];
    ws[1][tid] = ((const float4*)(wq + DM))[tid];
    ws[2][tid] = ((const float4*)(wk))[tid];
    ws[3][tid] = ((const float4*)(wk + DM))[tid];

    if (tid < 8) rep[row0 + tid] = SENTINEL;
    if (blockIdx.x == 0 && tid == 8) cnt[0] = 0;
    __syncthreads();

    const int wave = tid >> 6, lane = tid & 63;

    #pragma unroll
    for (int g = 0; g < 2; ++g) {
        const int row = row0 + g * 4 + wave;
        const float4* xr = (const float4*)(x + (size_t)row * DM);

        float s0 = 0.f, s1 = 0.f, s2 = 0.f, s3 = 0.f;
        #pragma unroll
        for (int j = 0; j < 4; ++j) {
            const float4 xv = xr[j * 64 + lane];
            s0 += dot4(xv, ws[0][j * 64 + lane]);
            s1 += dot4(xv, ws[1][j * 64 + lane]);
            s2 += dot4(xv, ws[2][j * 64 + lane]);
            s3 += dot4(xv, ws[3][j * 64 + lane]);
        }
        #pragma unroll
        for (int off = 32; off > 0; off >>= 1) {
            s0 += __shfl_down(s0, off);
            s1 += __shfl_down(s1, off);
            s2 += __shfl_down(s2, off);
            s3 += __shfl_down(s3, off);
        }
        if (lane == 0) {
            ((float2*)Q)[row] = make_float2(s0, s1);
            ((float2*)K)[row] = make_float2(s2, s3);
        }
    }
}

// ---------- Kernel 2: causal argmax. Paired tiles (j, 1023-j) per block:
//            K prefix staged ONCE (small tile's prefix is a subset of big's),
//            float4 staging, constant compute per block. ----------
__global__ __launch_bounds__(256) void argmax_kernel(const float* __restrict__ Q,
                                                     const float* __restrict__ K,
                                                     int* __restrict__ idx,
                                                     int* __restrict__ rep,
                                                     int* __restrict__ list,
                                                     int* __restrict__ cnt) {
    __shared__ float2 ks[TT];   // 32 KB
    const int b = blockIdx.x >> 9;
    const int j = blockIdx.x & 511;           // pair: tg = 1023-j (big), j (small)
    const int tid = threadIdx.x;

    // stage the BIG tile's prefix once; nfill = (1023-j)*4+4 float2s, mult of 2
    const int nfill4 = (((1023 - j) * 4 + 4) >> 1);   // float4 count
    const float4* kb4 = (const float4*)(K + (size_t)b * TT * 2);
    float4* ks4 = (float4*)ks;
    for (int i = tid; i < nfill4; i += 256) ks4[i] = kb4[i];
    __syncthreads();

    const int wave = tid >> 6, lane = tid & 63;
    const float4* kp = (const float4*)ks;   // pair p -> points 2p, 2p+1

    #pragma unroll
    for (int u = 0; u < 2; ++u) {
        const int tg = u ? j : (1023 - j);
        const int t = tg * 4 + wave;
        const float2 q = ((const float2*)Q)[b * TT + t];

        float best = -INFINITY;
        int bi = SENTINEL;
        int p = lane;
        // main: both pairs fully in range; in-lane ascending s order + strict '>'
        while (2 * (p + 64) + 1 <= t) {
            const float4 a = kp[p];
            const float4 c = kp[p + 64];
            const float c0 = q.x * a.x + q.y * a.y;
            const float c1 = q.x * a.z + q.y * a.w;
            const float c2 = q.x * c.x + q.y * c.y;
            const float c3 = q.x * c.z + q.y * c.w;
            if (c0 > best) { best = c0; bi = 2 * p; }
            if (c1 > best) { best = c1; bi = 2 * p + 1; }
            if (c2 > best) { best = c2; bi = 2 * (p + 64); }
            if (c3 > best) { best = c3; bi = 2 * (p + 64) + 1; }
            p += 128;
        }
        while (2 * p <= t) {
            const float4 a = kp[p];
            const float c0 = q.x * a.x + q.y * a.y;
            if (c0 > best) { best = c0; bi = 2 * p; }
            if (2 * p + 1 <= t) {
                const float c1 = q.x * a.z + q.y * a.w;
                if (c1 > best) { best = c1; bi = 2 * p + 1; }
            }
            p += 64;
        }
        // cross-lane argmax, first-occurrence tie-break
        #pragma unroll
        for (int off = 32; off > 0; off >>= 1) {
            const float ov = __shfl_down(best, off);
            const int   oi = __shfl_down(bi, off);
            if (ov > best || (ov == best && oi < bi)) { best = ov; bi = oi; }
        }
        if (lane == 0) {
            idx[b * TT + t] = bi;
            const int old = atomicMin(&rep[b * TT + bi], t);
            if (old == SENTINEL) {
                const int pp = atomicAdd(cnt, 1);
                list[pp] = b * TT + bi;
            }
        }
        // no __syncthreads needed: LDS is read-only across both tiles
    }
}

// ---------- Kernel 3: V-rows. 64 slices x 16 cols; wave owns 4 cols in 64 VGPRs;
//            16-way usub split over unique rows. ----------
__global__ __launch_bounds__(256) void vrow_kernel(const float* __restrict__ x,
                                                   const float* __restrict__ wv,
                                                   const int* __restrict__ rep,
                                                   const int* __restrict__ list,
                                                   const int* __restrict__ cnt,
                                                   float* __restrict__ out) {
    const int tid = threadIdx.x, wave = tid >> 6, lane = tid & 63;
    const int slice = blockIdx.x >> 4;     // [0,64): W_V rows slice*16 .. slice*16+15
    const int usub  = blockIdx.x & 15;
    const int e0 = slice * 16 + wave * 4;  // 4 output elements owned by this wave

    float4 w[4][4];
    #pragma unroll
    for (int r = 0; r < 4; ++r) {
        const float4* wr = (const float4*)(wv + (size_t)(e0 + r) * DM);
        #pragma unroll
        for (int j = 0; j < 4; ++j) w[r][j] = wr[j * 64 + lane];
    }

    const int n = cnt[0];
    for (int li = usub; li < n; li += 16) {
        const int bs = list[li];
        const int b  = bs >> 12;
        const int r  = rep[bs];
        const float4* xr = (const float4*)(x + (size_t)bs * DM);
        float4 xv[4];
        #pragma unroll
        for (int j = 0; j < 4; ++j) xv[j] = xr[j * 64 + lane];

        float s0 = 0.f, s1 = 0.f, s2 = 0.f, s3 = 0.f;
        #pragma unroll
        for (int j = 0; j < 4; ++j) {
            s0 += dot4(w[0][j], xv[j]);
            s1 += dot4(w[1][j], xv[j]);
            s2 += dot4(w[2][j], xv[j]);
            s3 += dot4(w[3][j], xv[j]);
        }
        #pragma unroll
        for (int off = 32; off > 0; off >>= 1) {
            s0 += __shfl_down(s0, off);
            s1 += __shfl_down(s1, off);
            s2 += __shfl_down(s2, off);
            s3 += __shfl_down(s3, off);
        }
        if (lane == 0)
            *(float4*)(out + ((size_t)(b * TT + r)) * DM + e0) = make_float4(s0, s1, s2, s3);
    }
}

// ---------- Kernel 4: broadcast representative rows to all t.
//            4 rows per block (wave-per-row) to amortize the idx->rep chain. ----------
__global__ __launch_bounds__(256) void gather_kernel(const int* __restrict__ idx,
                                                     const int* __restrict__ rep,
                                                     float* __restrict__ out) {
    const int tid = threadIdx.x, wave = tid >> 6, lane = tid & 63;
    const int bt = blockIdx.x * 4 + wave;
    const int b = bt >> 12, t = bt & (TT - 1);
    const int s = idx[bt];
    const int r = rep[b * TT + s];
    if (r == t) return;                       // wave-uniform
    const float4* src = (const float4*)(out + ((size_t)(b * TT + r)) * DM);
    float4* dst = (float4*)(out + (size_t)bt * DM);
    #pragma unroll
    for (int k = 0; k < 4; ++k) dst[k * 64 + lane] = src[k * 64 + lane];
}

extern "C" void kernel_launch(void* const* d_in, const int* in_sizes, int n_in,
                              void* d_out, int out_size, void* d_ws, size_t ws_size,
                              hipStream_t stream) {
    const float* x  = (const float*)d_in[0];
    const float* wq = (const float*)d_in[1];
    const float* wk = (const float*)d_in[2];
    const float* wv = (const float*)d_in[3];
    float* out = (float*)d_out;

    char* ws = (char*)d_ws;
    float* Q    = (float*)(ws);
    float* K    = (float*)(ws + 131072);
    int*   idx  = (int*)  (ws + 262144);
    int*   rep  = (int*)  (ws + 327680);
    int*   list = (int*)  (ws + 393216);
    int*   cnt  = (int*)  (ws + 458752);

    qk_kernel<<<BT / 8, 256, 0, stream>>>(x, wq, wk, Q, K, rep, cnt);
    argmax_kernel<<<BB * 512, 256, 0, stream>>>(Q, K, idx, rep, list, cnt);
    vrow_kernel<<<1024, 256, 0, stream>>>(x, wv, rep, list, cnt, out);
    gather_kernel<<<BT / 4, 256, 0, stream>>>(idx, rep, out);
}